// Round 2
// baseline (879.126 us; speedup 1.0000x reference)
//
#include <hip/hip_runtime.h>
#include <hip/hip_cooperative_groups.h>
#include <math.h>

namespace cg = cooperative_groups;

namespace {
constexpr int B = 32, H = 56, W = 56, C = 256;
constexpr int HW  = H * W;      // 3136
constexpr int WC  = W * C;      // 14336
constexpr int HC  = H * C;      // 14336
constexpr int HWC = H * W * C;  // 802816
constexpr int CH  = 32;         // SE hidden
constexpr float BN_EPS = 1e-3f;

constexpr int NPOOL_TASKS = 2 * B * H;            // 3584 (row tasks + col tasks)
constexpr int NCONV_TASKS = B * H + B * W + (B * HW) / 256;  // 1792+1792+392 = 3976
constexpr int NHALF_TASKS = B * H * 2;            // 3584 half-row tasks

__device__ __forceinline__ float sigmoidf_(float v) { return 1.0f / (1.0f + expf(-v)); }
} // namespace

__global__ __launch_bounds__(256, 4)
void fused_trise_kernel(const float* __restrict__ x,
                        const float* __restrict__ c1w, const float* __restrict__ c1b,
                        const float* __restrict__ g1,  const float* __restrict__ be1,
                        const float* __restrict__ m1,  const float* __restrict__ v1,
                        const float* __restrict__ c2w, const float* __restrict__ c2b,
                        const float* __restrict__ g2,  const float* __restrict__ be2,
                        const float* __restrict__ m2,  const float* __restrict__ v2,
                        const float* __restrict__ c3w, const float* __restrict__ c3b,
                        const float* __restrict__ g3,  const float* __restrict__ be3,
                        const float* __restrict__ m3,  const float* __restrict__ v3,
                        const float* __restrict__ sw1, const float* __restrict__ sb1,
                        const float* __restrict__ sw2, const float* __restrict__ sb2,
                        float* __restrict__ ws, float* __restrict__ out) {
    // ---- workspace carve-up (floats) ----
    float* pmax1 = ws;                                // [B][H][C]
    float* pavg1 = pmax1 + (size_t)B * HC;
    float* pmax2 = pavg1 + (size_t)B * HC;            // [B][W][C]
    float* pavg2 = pmax2 + (size_t)B * WC;
    float* pmax3 = pavg2 + (size_t)B * WC;            // [B][H][W]
    float* pavg3 = pmax3 + (size_t)B * HW;
    float* a1    = pavg3 + (size_t)B * HW;            // [B][H][C]
    float* a2t   = a1    + (size_t)B * HC;            // [B][W][C]
    float* a3    = a2t   + (size_t)B * WC;            // [B][H][W]
    float* gpart = a3    + (size_t)B * HW;            // [NHALF_TASKS][C]
    float* cw    = gpart + (size_t)NHALF_TASKS * C;   // [B][C]

    __shared__ float smx[4][256];
    __shared__ float ssm[4][256];
    __shared__ float wc0[98], wc1[98], wc2[98];
    __shared__ float sbnA[3], sbnB[3];
    __shared__ float gs[C];
    __shared__ float hsh[CH];

    const int nb   = gridDim.x;
    const int t    = threadIdx.x;
    const int lane = t & 63, sub = t >> 6;
    const int c4   = lane * 4;

    // preload conv weights + folded BN constants
    if (t < 98) { wc0[t] = c1w[t]; wc1[t] = c2w[t]; wc2[t] = c3w[t]; }
    if (t == 0) { float A = rsqrtf(v1[0] + BN_EPS) * g1[0]; sbnA[0] = A; sbnB[0] = (c1b[0] - m1[0]) * A + be1[0]; }
    if (t == 1) { float A = rsqrtf(v2[0] + BN_EPS) * g2[0]; sbnA[1] = A; sbnB[1] = (c2b[0] - m2[0]) * A + be2[0]; }
    if (t == 2) { float A = rsqrtf(v3[0] + BN_EPS) * g3[0]; sbnA[2] = A; sbnB[2] = (c3b[0] - m3[0]) * A + be3[0]; }

    cg::grid_group grid = cg::this_grid();

    // ================= Phase 1: pools (one x read per task family) ==========
    for (int tt = blockIdx.x; tt < NPOOL_TASKS; tt += nb) {
        if (tt < B * H) {
            // pool over W (branch1) + pool over C (branch3) for row (b,h)
            const int b = tt / H, h = tt % H;
            const float* xp = x + (size_t)b * HWC + (size_t)h * WC;
            float4 mx = make_float4(-INFINITY, -INFINITY, -INFINITY, -INFINITY);
            float4 sm = make_float4(0.f, 0.f, 0.f, 0.f);
            for (int wq = 0; wq < 14; ++wq) {
                const int w = wq * 4 + sub;
                const float4 v = *(const float4*)(xp + w * C + c4);
                mx.x = fmaxf(mx.x, v.x); mx.y = fmaxf(mx.y, v.y);
                mx.z = fmaxf(mx.z, v.z); mx.w = fmaxf(mx.w, v.w);
                sm.x += v.x; sm.y += v.y; sm.z += v.z; sm.w += v.w;
                float m3v = fmaxf(fmaxf(v.x, v.y), fmaxf(v.z, v.w));
                float s3v = v.x + v.y + v.z + v.w;
                #pragma unroll
                for (int off = 32; off > 0; off >>= 1) {
                    m3v = fmaxf(m3v, __shfl_down(m3v, off));
                    s3v += __shfl_down(s3v, off);
                }
                if (lane == 0) {
                    pmax3[b * HW + h * W + w] = m3v;
                    pavg3[b * HW + h * W + w] = s3v * (1.0f / C);
                }
            }
            __syncthreads();
            *(float4*)&smx[sub][c4] = mx;
            *(float4*)&ssm[sub][c4] = sm;
            __syncthreads();
            const float m = fmaxf(fmaxf(smx[0][t], smx[1][t]), fmaxf(smx[2][t], smx[3][t]));
            const float s = ssm[0][t] + ssm[1][t] + ssm[2][t] + ssm[3][t];
            pmax1[b * HC + h * C + t] = m;
            pavg1[b * HC + h * C + t] = s * (1.0f / W);
        } else {
            // pool over H (branch2) for column (b,w), stored [b][w][c]
            const int tt2 = tt - B * H;
            const int b = tt2 / W, w = tt2 % W;
            const float* xp = x + (size_t)b * HWC + (size_t)w * C;
            float4 mx = make_float4(-INFINITY, -INFINITY, -INFINITY, -INFINITY);
            float4 sm = make_float4(0.f, 0.f, 0.f, 0.f);
            for (int hq = 0; hq < 14; ++hq) {
                const int h = hq * 4 + sub;
                const float4 v = *(const float4*)(xp + (size_t)h * WC + c4);
                mx.x = fmaxf(mx.x, v.x); mx.y = fmaxf(mx.y, v.y);
                mx.z = fmaxf(mx.z, v.z); mx.w = fmaxf(mx.w, v.w);
                sm.x += v.x; sm.y += v.y; sm.z += v.z; sm.w += v.w;
            }
            __syncthreads();
            *(float4*)&smx[sub][c4] = mx;
            *(float4*)&ssm[sub][c4] = sm;
            __syncthreads();
            const float m = fmaxf(fmaxf(smx[0][t], smx[1][t]), fmaxf(smx[2][t], smx[3][t]));
            const float s = ssm[0][t] + ssm[1][t] + ssm[2][t] + ssm[3][t];
            pmax2[b * WC + w * C + t] = m;
            pavg2[b * WC + w * C + t] = s * (1.0f / H);
        }
    }
    __threadfence();
    grid.sync();

    // ================= Phase 2: the three 7x7 convs + BN + sigmoid ==========
    for (int tt = blockIdx.x; tt < NCONV_TASKS; tt += nb) {
        if (tt < B * H) {
            // conv1: spatial (H, C), out a1[b][h][c]
            const int b = tt / H, h = tt % H;
            const int c = t;
            const float A = sbnA[0], Bc = sbnB[0];
            float acc = 0.f;
            const float* bm = pmax1 + b * HC;
            const float* ba = pavg1 + b * HC;
            #pragma unroll
            for (int ky = 0; ky < 7; ++ky) {
                const int hy = h + ky - 3;
                if (hy < 0 || hy >= H) continue;
                const float* rm = bm + hy * C;
                const float* ra = ba + hy * C;
                #pragma unroll
                for (int kx = 0; kx < 7; ++kx) {
                    const int cx = c + kx - 3;
                    if (cx < 0 || cx >= C) continue;
                    acc += rm[cx] * wc0[ky * 14 + kx * 2] + ra[cx] * wc0[ky * 14 + kx * 2 + 1];
                }
            }
            a1[b * HC + h * C + c] = sigmoidf_(acc * A + Bc);
        } else if (tt < 2 * B * H) {
            // conv2: spatial (C, W); pool stored [b][w][c]; out a2t[b][w][c]
            const int tt2 = tt - B * H;
            const int b = tt2 / W, w = tt2 % W;
            const int c = t;
            const float A = sbnA[1], Bc = sbnB[1];
            float acc = 0.f;
            #pragma unroll
            for (int kx = 0; kx < 7; ++kx) {
                const int wx = w + kx - 3;
                if (wx < 0 || wx >= W) continue;
                const float* rm = pmax2 + b * WC + wx * C;
                const float* ra = pavg2 + b * WC + wx * C;
                #pragma unroll
                for (int ky = 0; ky < 7; ++ky) {
                    const int cy = c + ky - 3;
                    if (cy < 0 || cy >= C) continue;
                    acc += rm[cy] * wc1[ky * 14 + kx * 2] + ra[cy] * wc1[ky * 14 + kx * 2 + 1];
                }
            }
            a2t[b * WC + w * C + c] = sigmoidf_(acc * A + Bc);
        } else {
            // conv3: spatial (H, W), out a3[b][h][w]
            const int gid = (tt - 2 * B * H) * 256 + t;
            const int b = gid / HW;
            const int hw = gid % HW;
            const int h = hw / W, w = hw % W;
            const float A = sbnA[2], Bc = sbnB[2];
            float acc = 0.f;
            const float* bm = pmax3 + b * HW;
            const float* ba = pavg3 + b * HW;
            #pragma unroll
            for (int ky = 0; ky < 7; ++ky) {
                const int hy = h + ky - 3;
                if (hy < 0 || hy >= H) continue;
                #pragma unroll
                for (int kx = 0; kx < 7; ++kx) {
                    const int wx = w + kx - 3;
                    if (wx < 0 || wx >= W) continue;
                    acc += bm[hy * W + wx] * wc2[ky * 14 + kx * 2] + ba[hy * W + wx] * wc2[ky * 14 + kx * 2 + 1];
                }
            }
            a3[b * HW + hw] = sigmoidf_(acc * A + Bc);
        }
    }
    __threadfence();
    grid.sync();

    // ================= Phase 3: gap partials (half-row tasks) ===============
    for (int tt = blockIdx.x; tt < NHALF_TASKS; tt += nb) {
        const int b = tt / (2 * H);
        const int rem = tt % (2 * H);
        const int h = rem >> 1, half = rem & 1;
        const float* xp  = x   + (size_t)b * HWC + (size_t)h * WC;
        const float* a2b = a2t + (size_t)b * WC;
        const float4 a1v = *(const float4*)(a1 + b * HC + h * C + c4);
        float4 acc = make_float4(0.f, 0.f, 0.f, 0.f);
        for (int wq = 0; wq < 7; ++wq) {
            const int w = half * 28 + wq * 4 + sub;
            const float4 xv  = *(const float4*)(xp  + w * C + c4);
            const float4 a2v = *(const float4*)(a2b + w * C + c4);
            const float a3v  = a3[b * HW + h * W + w];
            acc.x += xv.x * (a1v.x + a2v.x + a3v);
            acc.y += xv.y * (a1v.y + a2v.y + a3v);
            acc.z += xv.z * (a1v.z + a2v.z + a3v);
            acc.w += xv.w * (a1v.w + a2v.w + a3v);
        }
        __syncthreads();
        *(float4*)&smx[sub][c4] = acc;
        __syncthreads();
        gpart[(size_t)tt * C + t] = smx[0][t] + smx[1][t] + smx[2][t] + smx[3][t];
    }
    __threadfence();
    grid.sync();

    // ================= Phase 4: SE (blocks 0..B-1 only) =====================
    if (blockIdx.x < B) {
        const int b = blockIdx.x;
        float s = 0.f;
        for (int r = 0; r < 2 * H; ++r) s += gpart[(size_t)(b * 2 * H + r) * C + t];
        gs[t] = s * (1.0f / (float)HW);
        __syncthreads();
        if (t < CH) {
            float a = sb1[t];
            for (int c = 0; c < C; ++c) a += gs[c] * sw1[c * CH + t];
            hsh[t] = fmaxf(a, 0.f);
        }
        __syncthreads();
        float a = sb2[t];
        #pragma unroll
        for (int d = 0; d < CH; ++d) a += hsh[d] * sw2[d * C + t];
        cw[b * C + t] = sigmoidf_(a);
    }
    __threadfence();
    grid.sync();

    // ================= Phase 5: out = x*(a1+a2+a3)*cw (half-row tasks) ======
    for (int tt = blockIdx.x; tt < NHALF_TASKS; tt += nb) {
        const int b = tt / (2 * H);
        const int rem = tt % (2 * H);
        const int h = rem >> 1, half = rem & 1;
        const float* xp  = x   + (size_t)b * HWC + (size_t)h * WC;
        const float* a2b = a2t + (size_t)b * WC;
        float*       op  = out + (size_t)b * HWC + (size_t)h * WC;
        const float4 a1v = *(const float4*)(a1 + b * HC + h * C + c4);
        const float4 cwv = *(const float4*)(cw + b * C + c4);
        for (int wq = 0; wq < 7; ++wq) {
            const int w = half * 28 + wq * 4 + sub;
            const float4 xv  = *(const float4*)(xp  + w * C + c4);
            const float4 a2v = *(const float4*)(a2b + w * C + c4);
            const float a3v  = a3[b * HW + h * W + w];
            float4 o;
            o.x = xv.x * (a1v.x + a2v.x + a3v) * cwv.x;
            o.y = xv.y * (a1v.y + a2v.y + a3v) * cwv.y;
            o.z = xv.z * (a1v.z + a2v.z + a3v) * cwv.z;
            o.w = xv.w * (a1v.w + a2v.w + a3v) * cwv.w;
            *(float4*)(op + w * C + c4) = o;
        }
    }
}

extern "C" void kernel_launch(void* const* d_in, const int* in_sizes, int n_in,
                              void* d_out, int out_size, void* d_ws, size_t ws_size,
                              hipStream_t stream) {
    const float* x   = (const float*)d_in[0];
    const float* c1w = (const float*)d_in[1];  const float* c1b = (const float*)d_in[2];
    const float* g1  = (const float*)d_in[3];  const float* be1 = (const float*)d_in[4];
    const float* m1  = (const float*)d_in[5];  const float* v1  = (const float*)d_in[6];
    const float* c2w = (const float*)d_in[7];  const float* c2b = (const float*)d_in[8];
    const float* g2  = (const float*)d_in[9];  const float* be2 = (const float*)d_in[10];
    const float* m2  = (const float*)d_in[11]; const float* v2  = (const float*)d_in[12];
    const float* c3w = (const float*)d_in[13]; const float* c3b = (const float*)d_in[14];
    const float* g3  = (const float*)d_in[15]; const float* be3 = (const float*)d_in[16];
    const float* m3  = (const float*)d_in[17]; const float* v3  = (const float*)d_in[18];
    const float* sw1 = (const float*)d_in[19]; const float* sb1 = (const float*)d_in[20];
    const float* sw2 = (const float*)d_in[21]; const float* sb2 = (const float*)d_in[22];
    float* ws  = (float*)d_ws;
    float* out = (float*)d_out;

    // size the cooperative grid to guaranteed co-residency
    int nbpc = 0;
    hipOccupancyMaxActiveBlocksPerMultiprocessor(&nbpc, fused_trise_kernel, 256, 0);
    if (nbpc < 1) nbpc = 1;
    int grid = nbpc * 256;                 // 256 CUs on MI355X
    if (grid > NPOOL_TASKS) grid = NPOOL_TASKS;

    void* args[] = {
        (void*)&x,
        (void*)&c1w, (void*)&c1b, (void*)&g1, (void*)&be1, (void*)&m1, (void*)&v1,
        (void*)&c2w, (void*)&c2b, (void*)&g2, (void*)&be2, (void*)&m2, (void*)&v2,
        (void*)&c3w, (void*)&c3b, (void*)&g3, (void*)&be3, (void*)&m3, (void*)&v3,
        (void*)&sw1, (void*)&sb1, (void*)&sw2, (void*)&sb2,
        (void*)&ws, (void*)&out,
    };
    hipLaunchCooperativeKernel((const void*)fused_trise_kernel, dim3(grid), dim3(256),
                               args, 0, stream);
}

// Round 3
// 311.947 us; speedup vs baseline: 2.8182x; 2.8182x over previous
//
#include <hip/hip_runtime.h>
#include <math.h>

namespace {
constexpr int B = 32, H = 56, W = 56, C = 256;
constexpr int HW  = H * W;      // 3136
constexpr int WC  = W * C;      // 14336
constexpr int HC  = H * C;      // 14336
constexpr int HWC = H * W * C;  // 802816
constexpr int CH  = 32;         // SE hidden
constexpr float BN_EPS = 1e-3f;

__device__ __forceinline__ float sigmoidf_(float v) { return 1.0f / (1.0f + expf(-v)); }
} // namespace

// ============ K1: all pools in one dispatch ==================================
// blocks [0, B*H): pool over W (branch1) + pool over C (branch3) for row (b,h)
// blocks [B*H, B*H+B*W): pool over H (branch2) for col (b,w), stored [b][w][c]
__global__ __launch_bounds__(256)
void pool_all_kernel(const float* __restrict__ x,
                     float* __restrict__ pmax1, float* __restrict__ pavg1,
                     float* __restrict__ pmax2, float* __restrict__ pavg2,
                     float* __restrict__ pmax3, float* __restrict__ pavg3) {
    const int t = threadIdx.x;
    const int lane = t & 63, sub = t >> 6;
    const int c4 = lane * 4;
    __shared__ float smx[4][256];
    __shared__ float ssm[4][256];

    if (blockIdx.x < B * H) {
        const int b = blockIdx.x / H, h = blockIdx.x % H;
        const float* xp = x + (size_t)b * HWC + (size_t)h * WC;
        float4 mx = make_float4(-INFINITY, -INFINITY, -INFINITY, -INFINITY);
        float4 sm = make_float4(0.f, 0.f, 0.f, 0.f);
        for (int wq = 0; wq < 14; ++wq) {
            const int w = wq * 4 + sub;
            const float4 v = *(const float4*)(xp + w * C + c4);
            mx.x = fmaxf(mx.x, v.x); mx.y = fmaxf(mx.y, v.y);
            mx.z = fmaxf(mx.z, v.z); mx.w = fmaxf(mx.w, v.w);
            sm.x += v.x; sm.y += v.y; sm.z += v.z; sm.w += v.w;
            float m3 = fmaxf(fmaxf(v.x, v.y), fmaxf(v.z, v.w));
            float s3 = v.x + v.y + v.z + v.w;
            #pragma unroll
            for (int off = 32; off > 0; off >>= 1) {
                m3 = fmaxf(m3, __shfl_down(m3, off));
                s3 += __shfl_down(s3, off);
            }
            if (lane == 0) {
                pmax3[b * HW + h * W + w] = m3;
                pavg3[b * HW + h * W + w] = s3 * (1.0f / C);
            }
        }
        *(float4*)&smx[sub][c4] = mx;
        *(float4*)&ssm[sub][c4] = sm;
        __syncthreads();
        const float m = fmaxf(fmaxf(smx[0][t], smx[1][t]), fmaxf(smx[2][t], smx[3][t]));
        const float s = ssm[0][t] + ssm[1][t] + ssm[2][t] + ssm[3][t];
        pmax1[b * HC + h * C + t] = m;
        pavg1[b * HC + h * C + t] = s * (1.0f / W);
    } else {
        const int tt = blockIdx.x - B * H;
        const int b = tt / W, w = tt % W;
        const float* xp = x + (size_t)b * HWC + (size_t)w * C;
        float4 mx = make_float4(-INFINITY, -INFINITY, -INFINITY, -INFINITY);
        float4 sm = make_float4(0.f, 0.f, 0.f, 0.f);
        for (int hq = 0; hq < 14; ++hq) {
            const int h = hq * 4 + sub;
            const float4 v = *(const float4*)(xp + (size_t)h * WC + c4);
            mx.x = fmaxf(mx.x, v.x); mx.y = fmaxf(mx.y, v.y);
            mx.z = fmaxf(mx.z, v.z); mx.w = fmaxf(mx.w, v.w);
            sm.x += v.x; sm.y += v.y; sm.z += v.z; sm.w += v.w;
        }
        *(float4*)&smx[sub][c4] = mx;
        *(float4*)&ssm[sub][c4] = sm;
        __syncthreads();
        const float m = fmaxf(fmaxf(smx[0][t], smx[1][t]), fmaxf(smx[2][t], smx[3][t]));
        const float s = ssm[0][t] + ssm[1][t] + ssm[2][t] + ssm[3][t];
        pmax2[b * WC + w * C + t] = m;
        pavg2[b * WC + w * C + t] = s * (1.0f / H);
    }
}

// ============ K2: all three 7x7 convs + BN + sigmoid in one dispatch =========
__global__ __launch_bounds__(256)
void conv_all_kernel(const float* __restrict__ pmax1, const float* __restrict__ pavg1,
                     const float* __restrict__ pmax2, const float* __restrict__ pavg2,
                     const float* __restrict__ pmax3, const float* __restrict__ pavg3,
                     const float* __restrict__ c1w, const float* __restrict__ c1b,
                     const float* __restrict__ g1,  const float* __restrict__ be1,
                     const float* __restrict__ m1,  const float* __restrict__ v1,
                     const float* __restrict__ c2w, const float* __restrict__ c2b,
                     const float* __restrict__ g2,  const float* __restrict__ be2,
                     const float* __restrict__ m2,  const float* __restrict__ v2,
                     const float* __restrict__ c3w, const float* __restrict__ c3b,
                     const float* __restrict__ g3,  const float* __restrict__ be3,
                     const float* __restrict__ m3,  const float* __restrict__ v3,
                     float* __restrict__ a1, float* __restrict__ a2t, float* __restrict__ a3) {
    const int t = threadIdx.x;
    __shared__ float wg[98];

    if (blockIdx.x < B * H) {
        // conv1: spatial (H, C), out a1[b][h][c]
        if (t < 98) wg[t] = c1w[t];
        __syncthreads();
        const int b = blockIdx.x / H, h = blockIdx.x % H;
        const float A  = rsqrtf(v1[0] + BN_EPS) * g1[0];
        const float Bc = (c1b[0] - m1[0]) * A + be1[0];
        float acc = 0.f;
        const float* bm = pmax1 + b * HC;
        const float* ba = pavg1 + b * HC;
        #pragma unroll
        for (int ky = 0; ky < 7; ++ky) {
            const int hy = h + ky - 3;
            if (hy < 0 || hy >= H) continue;
            const float* rm = bm + hy * C;
            const float* ra = ba + hy * C;
            #pragma unroll
            for (int kx = 0; kx < 7; ++kx) {
                const int cx = t + kx - 3;
                if (cx < 0 || cx >= C) continue;
                acc += rm[cx] * wg[ky * 14 + kx * 2] + ra[cx] * wg[ky * 14 + kx * 2 + 1];
            }
        }
        a1[b * HC + h * C + t] = sigmoidf_(acc * A + Bc);
    } else if (blockIdx.x < 2 * B * H) {
        // conv2: spatial (C, W); pools stored [b][w][c]; out a2t[b][w][c]
        if (t < 98) wg[t] = c2w[t];
        __syncthreads();
        const int tt = blockIdx.x - B * H;
        const int b = tt / W, w = tt % W;
        const float A  = rsqrtf(v2[0] + BN_EPS) * g2[0];
        const float Bc = (c2b[0] - m2[0]) * A + be2[0];
        float acc = 0.f;
        #pragma unroll
        for (int kx = 0; kx < 7; ++kx) {
            const int wx = w + kx - 3;
            if (wx < 0 || wx >= W) continue;
            const float* rm = pmax2 + b * WC + wx * C;
            const float* ra = pavg2 + b * WC + wx * C;
            #pragma unroll
            for (int ky = 0; ky < 7; ++ky) {
                const int cy = t + ky - 3;
                if (cy < 0 || cy >= C) continue;
                acc += rm[cy] * wg[ky * 14 + kx * 2] + ra[cy] * wg[ky * 14 + kx * 2 + 1];
            }
        }
        a2t[b * WC + w * C + t] = sigmoidf_(acc * A + Bc);
    } else {
        // conv3: spatial (H, W), out a3[b][h][w]
        if (t < 98) wg[t] = c3w[t];
        __syncthreads();
        const int gid = (blockIdx.x - 2 * B * H) * 256 + t;
        const int b = gid / HW;
        const int hw = gid % HW;
        const int h = hw / W, w = hw % W;
        const float A  = rsqrtf(v3[0] + BN_EPS) * g3[0];
        const float Bc = (c3b[0] - m3[0]) * A + be3[0];
        float acc = 0.f;
        const float* bm = pmax3 + b * HW;
        const float* ba = pavg3 + b * HW;
        #pragma unroll
        for (int ky = 0; ky < 7; ++ky) {
            const int hy = h + ky - 3;
            if (hy < 0 || hy >= H) continue;
            #pragma unroll
            for (int kx = 0; kx < 7; ++kx) {
                const int wx = w + kx - 3;
                if (wx < 0 || wx >= W) continue;
                acc += bm[hy * W + wx] * wg[ky * 14 + kx * 2] + ba[hy * W + wx] * wg[ky * 14 + kx * 2 + 1];
            }
        }
        a3[b * HW + hw] = sigmoidf_(acc * A + Bc);
    }
}

// ============ K3: per-row gap partials (no atomics, no memset) ===============
__global__ __launch_bounds__(256)
void gap_row_kernel(const float* __restrict__ x, const float* __restrict__ a1,
                    const float* __restrict__ a2t, const float* __restrict__ a3,
                    float* __restrict__ gpart) {
    const int b = blockIdx.x / H, h = blockIdx.x % H;
    const int t = threadIdx.x;
    const int lane = t & 63, sub = t >> 6;
    const int c4 = lane * 4;
    const float* xp  = x   + (size_t)b * HWC + (size_t)h * WC;
    const float* a2b = a2t + (size_t)b * WC;
    const float4 a1v = *(const float4*)(a1 + b * HC + h * C + c4);
    float4 acc = make_float4(0.f, 0.f, 0.f, 0.f);
    for (int wq = 0; wq < 14; ++wq) {
        const int w = wq * 4 + sub;
        const float4 xv  = *(const float4*)(xp  + w * C + c4);
        const float4 a2v = *(const float4*)(a2b + w * C + c4);
        const float a3v  = a3[b * HW + h * W + w];
        acc.x += xv.x * (a1v.x + a2v.x + a3v);
        acc.y += xv.y * (a1v.y + a2v.y + a3v);
        acc.z += xv.z * (a1v.z + a2v.z + a3v);
        acc.w += xv.w * (a1v.w + a2v.w + a3v);
    }
    __shared__ float sacc[4][256];
    *(float4*)&sacc[sub][c4] = acc;
    __syncthreads();
    gpart[(size_t)blockIdx.x * C + t] = sacc[0][t] + sacc[1][t] + sacc[2][t] + sacc[3][t];
}

// ============ K4: SE (gpart reduce + FC 256->32->256) ========================
__global__ __launch_bounds__(256)
void se_kernel(const float* __restrict__ gpart,
               const float* __restrict__ w1, const float* __restrict__ b1,
               const float* __restrict__ w2, const float* __restrict__ b2,
               float* __restrict__ cw) {
    const int b = blockIdx.x;
    const int t = threadIdx.x;
    __shared__ float gs[C];
    __shared__ float hs[CH];
    float s = 0.f;
    for (int r = 0; r < H; ++r) s += gpart[(size_t)(b * H + r) * C + t];
    gs[t] = s * (1.0f / (float)HW);
    __syncthreads();
    if (t < CH) {
        float a = b1[t];
        for (int c = 0; c < C; ++c) a += gs[c] * w1[c * CH + t];
        hs[t] = fmaxf(a, 0.f);
    }
    __syncthreads();
    float a = b2[t];
    #pragma unroll
    for (int d = 0; d < CH; ++d) a += hs[d] * w2[d * C + t];
    cw[b * C + t] = sigmoidf_(a);
}

// ============ K5: out = x*(a1+a2+a3)*cw, one row per block ===================
__global__ __launch_bounds__(256)
void out_row_kernel(const float* __restrict__ x, const float* __restrict__ a1,
                    const float* __restrict__ a2t, const float* __restrict__ a3,
                    const float* __restrict__ cw, float* __restrict__ out) {
    const int b = blockIdx.x / H, h = blockIdx.x % H;
    const int t = threadIdx.x;
    const int lane = t & 63, sub = t >> 6;
    const int c4 = lane * 4;
    const float* xp  = x   + (size_t)b * HWC + (size_t)h * WC;
    const float* a2b = a2t + (size_t)b * WC;
    float*       op  = out + (size_t)b * HWC + (size_t)h * WC;
    const float4 a1v = *(const float4*)(a1 + b * HC + h * C + c4);
    const float4 cwv = *(const float4*)(cw + b * C + c4);
    for (int wq = 0; wq < 14; ++wq) {
        const int w = wq * 4 + sub;
        const float4 xv  = *(const float4*)(xp  + w * C + c4);
        const float4 a2v = *(const float4*)(a2b + w * C + c4);
        const float a3v  = a3[b * HW + h * W + w];
        float4 o;
        o.x = xv.x * (a1v.x + a2v.x + a3v) * cwv.x;
        o.y = xv.y * (a1v.y + a2v.y + a3v) * cwv.y;
        o.z = xv.z * (a1v.z + a2v.z + a3v) * cwv.z;
        o.w = xv.w * (a1v.w + a2v.w + a3v) * cwv.w;
        *(float4*)(op + w * C + c4) = o;
    }
}

extern "C" void kernel_launch(void* const* d_in, const int* in_sizes, int n_in,
                              void* d_out, int out_size, void* d_ws, size_t ws_size,
                              hipStream_t stream) {
    const float* x   = (const float*)d_in[0];
    const float* c1w = (const float*)d_in[1];  const float* c1b = (const float*)d_in[2];
    const float* g1  = (const float*)d_in[3];  const float* be1 = (const float*)d_in[4];
    const float* m1  = (const float*)d_in[5];  const float* v1  = (const float*)d_in[6];
    const float* c2w = (const float*)d_in[7];  const float* c2b = (const float*)d_in[8];
    const float* g2  = (const float*)d_in[9];  const float* be2 = (const float*)d_in[10];
    const float* m2  = (const float*)d_in[11]; const float* v2  = (const float*)d_in[12];
    const float* c3w = (const float*)d_in[13]; const float* c3b = (const float*)d_in[14];
    const float* g3  = (const float*)d_in[15]; const float* be3 = (const float*)d_in[16];
    const float* m3  = (const float*)d_in[17]; const float* v3  = (const float*)d_in[18];
    const float* sw1 = (const float*)d_in[19]; const float* sb1 = (const float*)d_in[20];
    const float* sw2 = (const float*)d_in[21]; const float* sb2 = (const float*)d_in[22];

    float* ws = (float*)d_ws;
    float* pmax1 = ws;                       // [B][H][C]
    float* pavg1 = pmax1 + (size_t)B * HC;
    float* pmax2 = pavg1 + (size_t)B * HC;   // [B][W][C]
    float* pavg2 = pmax2 + (size_t)B * WC;
    float* pmax3 = pavg2 + (size_t)B * WC;   // [B][H][W]
    float* pavg3 = pmax3 + (size_t)B * HW;
    float* a1    = pavg3 + (size_t)B * HW;   // [B][H][C]
    float* a2t   = a1    + (size_t)B * HC;   // [B][W][C]
    float* a3    = a2t   + (size_t)B * WC;   // [B][H][W]
    float* gpart = a3    + (size_t)B * HW;   // [B*H][C]
    float* cwv   = gpart + (size_t)B * H * C;// [B][C]

    pool_all_kernel<<<B * H + B * W, 256, 0, stream>>>(x, pmax1, pavg1, pmax2, pavg2, pmax3, pavg3);
    conv_all_kernel<<<2 * B * H + (B * HW) / 256, 256, 0, stream>>>(
        pmax1, pavg1, pmax2, pavg2, pmax3, pavg3,
        c1w, c1b, g1, be1, m1, v1,
        c2w, c2b, g2, be2, m2, v2,
        c3w, c3b, g3, be3, m3, v3,
        a1, a2t, a3);
    gap_row_kernel<<<B * H, 256, 0, stream>>>(x, a1, a2t, a3, gpart);
    se_kernel<<<B, 256, 0, stream>>>(gpart, sw1, sb1, sw2, sb2, cwv);
    out_row_kernel<<<B * H, 256, 0, stream>>>(x, a1, a2t, a3, cwv, (float*)d_out);
}

// Round 4
// 295.831 us; speedup vs baseline: 2.9717x; 1.0545x over previous
//
#include <hip/hip_runtime.h>
#include <math.h>

namespace {
constexpr int B = 32, H = 56, W = 56, C = 256;
constexpr int HW  = H * W;      // 3136
constexpr int WC  = W * C;      // 14336
constexpr int HC  = H * C;      // 14336
constexpr int HWC = H * W * C;  // 802816
constexpr int CH  = 32;         // SE hidden
constexpr float BN_EPS = 1e-3f;

using f4v = __attribute__((ext_vector_type(4))) float;

__device__ __forceinline__ float sigmoidf_(float v) { return 1.0f / (1.0f + expf(-v)); }

__device__ __forceinline__ void nt_store_float4(float* p, const float4& o) {
    union { float4 s; f4v v; } u;
    u.s = o;
    __builtin_nontemporal_store(u.v, (f4v*)p);
}
} // namespace

// ============ K1: all pools in one dispatch ==================================
// blocks [0, B*H): row family -> pool1 (over W) + pool3 (over C) for row (b,h)
// blocks [B*H, B*H + B*14): col family -> pool2 (over H) for 4-col strip, [b][w][c]
__global__ __launch_bounds__(256)
void pool_all_kernel(const float* __restrict__ x,
                     float* __restrict__ pmax1, float* __restrict__ pavg1,
                     float* __restrict__ pmax2, float* __restrict__ pavg2,
                     float* __restrict__ pmax3, float* __restrict__ pavg3) {
    const int t = threadIdx.x;

    if (blockIdx.x < B * H) {
        const int lane = t & 63, sub = t >> 6;
        const int c4 = lane * 4;
        __shared__ float smx[4][256];
        __shared__ float ssm[4][256];
        const int b = blockIdx.x / H, h = blockIdx.x % H;
        const float* xp = x + (size_t)b * HWC + (size_t)h * WC;
        float4 mx = make_float4(-INFINITY, -INFINITY, -INFINITY, -INFINITY);
        float4 sm = make_float4(0.f, 0.f, 0.f, 0.f);
        for (int wq = 0; wq < 14; ++wq) {
            const int w = wq * 4 + sub;
            const float4 v = *(const float4*)(xp + w * C + c4);
            mx.x = fmaxf(mx.x, v.x); mx.y = fmaxf(mx.y, v.y);
            mx.z = fmaxf(mx.z, v.z); mx.w = fmaxf(mx.w, v.w);
            sm.x += v.x; sm.y += v.y; sm.z += v.z; sm.w += v.w;
            float m3 = fmaxf(fmaxf(v.x, v.y), fmaxf(v.z, v.w));
            float s3 = v.x + v.y + v.z + v.w;
            #pragma unroll
            for (int off = 32; off > 0; off >>= 1) {
                m3 = fmaxf(m3, __shfl_down(m3, off));
                s3 += __shfl_down(s3, off);
            }
            if (lane == 0) {
                pmax3[b * HW + h * W + w] = m3;
                pavg3[b * HW + h * W + w] = s3 * (1.0f / C);
            }
        }
        *(float4*)&smx[sub][c4] = mx;
        *(float4*)&ssm[sub][c4] = sm;
        __syncthreads();
        const float m = fmaxf(fmaxf(smx[0][t], smx[1][t]), fmaxf(smx[2][t], smx[3][t]));
        const float s = ssm[0][t] + ssm[1][t] + ssm[2][t] + ssm[3][t];
        pmax1[b * HC + h * C + t] = m;
        pavg1[b * HC + h * C + t] = s * (1.0f / W);
    } else {
        // col family: block handles (b, 4 consecutive w), thread owns (w_off, c4)
        const int tt = blockIdx.x - B * H;
        const int b = tt / 14, wq = tt % 14;
        const int w = wq * 4 + (t >> 6);
        const int c4 = (t & 63) * 4;
        const float* xp = x + (size_t)b * HWC + (size_t)w * C + c4;
        float4 mx = make_float4(-INFINITY, -INFINITY, -INFINITY, -INFINITY);
        float4 sm = make_float4(0.f, 0.f, 0.f, 0.f);
        #pragma unroll 8
        for (int h = 0; h < H; ++h) {
            const float4 v = *(const float4*)(xp + (size_t)h * WC);
            mx.x = fmaxf(mx.x, v.x); mx.y = fmaxf(mx.y, v.y);
            mx.z = fmaxf(mx.z, v.z); mx.w = fmaxf(mx.w, v.w);
            sm.x += v.x; sm.y += v.y; sm.z += v.z; sm.w += v.w;
        }
        const int oi = b * WC + w * C + c4;
        *(float4*)(pmax2 + oi) = mx;
        float4 av;
        av.x = sm.x * (1.0f / H); av.y = sm.y * (1.0f / H);
        av.z = sm.z * (1.0f / H); av.w = sm.w * (1.0f / H);
        *(float4*)(pavg2 + oi) = av;
    }
}

// ============ K2: all three 7x7 convs + BN + sigmoid in one dispatch =========
__global__ __launch_bounds__(256)
void conv_all_kernel(const float* __restrict__ pmax1, const float* __restrict__ pavg1,
                     const float* __restrict__ pmax2, const float* __restrict__ pavg2,
                     const float* __restrict__ pmax3, const float* __restrict__ pavg3,
                     const float* __restrict__ c1w, const float* __restrict__ c1b,
                     const float* __restrict__ g1,  const float* __restrict__ be1,
                     const float* __restrict__ m1,  const float* __restrict__ v1,
                     const float* __restrict__ c2w, const float* __restrict__ c2b,
                     const float* __restrict__ g2,  const float* __restrict__ be2,
                     const float* __restrict__ m2,  const float* __restrict__ v2,
                     const float* __restrict__ c3w, const float* __restrict__ c3b,
                     const float* __restrict__ g3,  const float* __restrict__ be3,
                     const float* __restrict__ m3,  const float* __restrict__ v3,
                     float* __restrict__ a1, float* __restrict__ a2t, float* __restrict__ a3) {
    const int t = threadIdx.x;
    __shared__ float wg[98];
    __shared__ float sm[7][264];
    __shared__ float sa[7][264];

    if (blockIdx.x < B * H) {
        // conv1: spatial (H, C), out a1[b][h][c]; LDS tile rows h-3..h+3
        if (t < 98) wg[t] = c1w[t];
        const int b = blockIdx.x / H, h = blockIdx.x % H;
        const float* bm = pmax1 + b * HC;
        const float* ba = pavg1 + b * HC;
        #pragma unroll
        for (int ky = 0; ky < 7; ++ky) {
            const int hy = h + ky - 3;
            const bool val = (hy >= 0 && hy < H);
            const int hyc = min(max(hy, 0), H - 1);
            const float lm = bm[hyc * C + t];
            const float la = ba[hyc * C + t];
            sm[ky][t + 3] = val ? lm : 0.f;
            sa[ky][t + 3] = val ? la : 0.f;
            if (t < 3) { sm[ky][t] = 0.f; sa[ky][t] = 0.f; sm[ky][261 - t] = 0.f; sa[ky][261 - t] = 0.f; }
        }
        __syncthreads();
        const float A  = rsqrtf(v1[0] + BN_EPS) * g1[0];
        const float Bc = (c1b[0] - m1[0]) * A + be1[0];
        float acc = 0.f;
        #pragma unroll
        for (int ky = 0; ky < 7; ++ky)
            #pragma unroll
            for (int kx = 0; kx < 7; ++kx)
                acc += sm[ky][t + kx] * wg[ky * 14 + kx * 2] + sa[ky][t + kx] * wg[ky * 14 + kx * 2 + 1];
        a1[b * HC + h * C + t] = sigmoidf_(acc * A + Bc);
    } else if (blockIdx.x < 2 * B * H) {
        // conv2: spatial (C, W); pools [b][w][c]; out a2t[b][w][c]; tile rows w-3..w+3
        if (t < 98) wg[t] = c2w[t];
        const int tt = blockIdx.x - B * H;
        const int b = tt / W, w = tt % W;
        #pragma unroll
        for (int kx = 0; kx < 7; ++kx) {
            const int wx = w + kx - 3;
            const bool val = (wx >= 0 && wx < W);
            const int wxc = min(max(wx, 0), W - 1);
            const float lm = pmax2[b * WC + wxc * C + t];
            const float la = pavg2[b * WC + wxc * C + t];
            sm[kx][t + 3] = val ? lm : 0.f;
            sa[kx][t + 3] = val ? la : 0.f;
            if (t < 3) { sm[kx][t] = 0.f; sa[kx][t] = 0.f; sm[kx][261 - t] = 0.f; sa[kx][261 - t] = 0.f; }
        }
        __syncthreads();
        const float A  = rsqrtf(v2[0] + BN_EPS) * g2[0];
        const float Bc = (c2b[0] - m2[0]) * A + be2[0];
        float acc = 0.f;
        #pragma unroll
        for (int kx = 0; kx < 7; ++kx)
            #pragma unroll
            for (int ky = 0; ky < 7; ++ky)
                acc += sm[kx][t + ky] * wg[ky * 14 + kx * 2] + sa[kx][t + ky] * wg[ky * 14 + kx * 2 + 1];
        a2t[b * WC + w * C + t] = sigmoidf_(acc * A + Bc);
    } else {
        // conv3: spatial (H, W), out a3[b][h][w]
        if (t < 98) wg[t] = c3w[t];
        __syncthreads();
        const int gid = (blockIdx.x - 2 * B * H) * 256 + t;
        const int b = gid / HW;
        const int hw = gid % HW;
        const int h = hw / W, w = hw % W;
        const float A  = rsqrtf(v3[0] + BN_EPS) * g3[0];
        const float Bc = (c3b[0] - m3[0]) * A + be3[0];
        float acc = 0.f;
        const float* bm = pmax3 + b * HW;
        const float* ba = pavg3 + b * HW;
        #pragma unroll
        for (int ky = 0; ky < 7; ++ky) {
            const int hy = h + ky - 3;
            if (hy < 0 || hy >= H) continue;
            #pragma unroll
            for (int kx = 0; kx < 7; ++kx) {
                const int wx = w + kx - 3;
                if (wx < 0 || wx >= W) continue;
                acc += bm[hy * W + wx] * wg[ky * 14 + kx * 2] + ba[hy * W + wx] * wg[ky * 14 + kx * 2 + 1];
            }
        }
        a3[b * HW + hw] = sigmoidf_(acc * A + Bc);
    }
}

// ============ K3: per-row a3-weighted partials: gpart[bh][c] = sum_w a3*x ====
__global__ __launch_bounds__(256)
void gap_row_kernel(const float* __restrict__ x, const float* __restrict__ a3,
                    float* __restrict__ gpart) {
    const int b = blockIdx.x / H, h = blockIdx.x % H;
    const int t = threadIdx.x;
    const int lane = t & 63, sub = t >> 6;
    const int c4 = lane * 4;
    const float* xp = x + (size_t)b * HWC + (size_t)h * WC;
    float4 acc = make_float4(0.f, 0.f, 0.f, 0.f);
    for (int wq = 0; wq < 14; ++wq) {
        const int w = wq * 4 + sub;
        const float4 xv = *(const float4*)(xp + w * C + c4);
        const float a3v = a3[b * HW + h * W + w];
        acc.x += xv.x * a3v;
        acc.y += xv.y * a3v;
        acc.z += xv.z * a3v;
        acc.w += xv.w * a3v;
    }
    __shared__ float sacc[4][256];
    *(float4*)&sacc[sub][c4] = acc;
    __syncthreads();
    gpart[(size_t)blockIdx.x * C + t] = sacc[0][t] + sacc[1][t] + sacc[2][t] + sacc[3][t];
}

// ============ K4: SE (analytic a1/a2 terms + gpart reduce + FC) ==============
__global__ __launch_bounds__(256)
void se_kernel(const float* __restrict__ gpart,
               const float* __restrict__ a1,  const float* __restrict__ pavg1,
               const float* __restrict__ a2t, const float* __restrict__ pavg2,
               const float* __restrict__ w1, const float* __restrict__ b1,
               const float* __restrict__ w2, const float* __restrict__ b2,
               float* __restrict__ cw) {
    const int b = blockIdx.x;
    const int t = threadIdx.x;
    __shared__ float gs[C];
    __shared__ float hs[CH];
    float s1 = 0.f, s2 = 0.f, s3 = 0.f;
    for (int r = 0; r < H; ++r) {
        s1 += a1 [b * HC + r * C + t] * pavg1[b * HC + r * C + t];
        s2 += a2t[b * WC + r * C + t] * pavg2[b * WC + r * C + t];
        s3 += gpart[(size_t)(b * H + r) * C + t];
    }
    // gap = s1*(W/HW) + s2*(H/HW) + s3/HW  = (s1+s2)/56 + s3/3136
    gs[t] = (s1 + s2) * (1.0f / 56.0f) + s3 * (1.0f / (float)HW);
    __syncthreads();
    if (t < CH) {
        float a = b1[t];
        for (int c = 0; c < C; ++c) a += gs[c] * w1[c * CH + t];
        hs[t] = fmaxf(a, 0.f);
    }
    __syncthreads();
    float a = b2[t];
    #pragma unroll
    for (int d = 0; d < CH; ++d) a += hs[d] * w2[d * C + t];
    cw[b * C + t] = sigmoidf_(a);
}

// ============ K5: out = x*(a1+a2+a3)*cw, one row per block ===================
__global__ __launch_bounds__(256)
void out_row_kernel(const float* __restrict__ x, const float* __restrict__ a1,
                    const float* __restrict__ a2t, const float* __restrict__ a3,
                    const float* __restrict__ cw, float* __restrict__ out) {
    const int b = blockIdx.x / H, h = blockIdx.x % H;
    const int t = threadIdx.x;
    const int lane = t & 63, sub = t >> 6;
    const int c4 = lane * 4;
    const float* xp  = x   + (size_t)b * HWC + (size_t)h * WC;
    const float* a2b = a2t + (size_t)b * WC;
    float*       op  = out + (size_t)b * HWC + (size_t)h * WC;
    const float4 a1v = *(const float4*)(a1 + b * HC + h * C + c4);
    const float4 cwv = *(const float4*)(cw + b * C + c4);
    for (int wq = 0; wq < 14; ++wq) {
        const int w = wq * 4 + sub;
        const float4 xv  = *(const float4*)(xp  + w * C + c4);
        const float4 a2v = *(const float4*)(a2b + w * C + c4);
        const float a3v  = a3[b * HW + h * W + w];
        float4 o;
        o.x = xv.x * (a1v.x + a2v.x + a3v) * cwv.x;
        o.y = xv.y * (a1v.y + a2v.y + a3v) * cwv.y;
        o.z = xv.z * (a1v.z + a2v.z + a3v) * cwv.z;
        o.w = xv.w * (a1v.w + a2v.w + a3v) * cwv.w;
        nt_store_float4(op + w * C + c4, o);
    }
}

extern "C" void kernel_launch(void* const* d_in, const int* in_sizes, int n_in,
                              void* d_out, int out_size, void* d_ws, size_t ws_size,
                              hipStream_t stream) {
    const float* x   = (const float*)d_in[0];
    const float* c1w = (const float*)d_in[1];  const float* c1b = (const float*)d_in[2];
    const float* g1  = (const float*)d_in[3];  const float* be1 = (const float*)d_in[4];
    const float* m1  = (const float*)d_in[5];  const float* v1  = (const float*)d_in[6];
    const float* c2w = (const float*)d_in[7];  const float* c2b = (const float*)d_in[8];
    const float* g2  = (const float*)d_in[9];  const float* be2 = (const float*)d_in[10];
    const float* m2  = (const float*)d_in[11]; const float* v2  = (const float*)d_in[12];
    const float* c3w = (const float*)d_in[13]; const float* c3b = (const float*)d_in[14];
    const float* g3  = (const float*)d_in[15]; const float* be3 = (const float*)d_in[16];
    const float* m3  = (const float*)d_in[17]; const float* v3  = (const float*)d_in[18];
    const float* sw1 = (const float*)d_in[19]; const float* sb1 = (const float*)d_in[20];
    const float* sw2 = (const float*)d_in[21]; const float* sb2 = (const float*)d_in[22];

    float* ws = (float*)d_ws;
    float* pmax1 = ws;                       // [B][H][C]
    float* pavg1 = pmax1 + (size_t)B * HC;
    float* pmax2 = pavg1 + (size_t)B * HC;   // [B][W][C]
    float* pavg2 = pmax2 + (size_t)B * WC;
    float* pmax3 = pavg2 + (size_t)B * WC;   // [B][H][W]
    float* pavg3 = pmax3 + (size_t)B * HW;
    float* a1    = pavg3 + (size_t)B * HW;   // [B][H][C]
    float* a2t   = a1    + (size_t)B * HC;   // [B][W][C]
    float* a3    = a2t   + (size_t)B * WC;   // [B][H][W]
    float* gpart = a3    + (size_t)B * HW;   // [B*H][C]
    float* cwv   = gpart + (size_t)B * H * C;// [B][C]

    pool_all_kernel<<<B * H + B * 14, 256, 0, stream>>>(x, pmax1, pavg1, pmax2, pavg2, pmax3, pavg3);
    conv_all_kernel<<<2 * B * H + (B * HW) / 256, 256, 0, stream>>>(
        pmax1, pavg1, pmax2, pavg2, pmax3, pavg3,
        c1w, c1b, g1, be1, m1, v1,
        c2w, c2b, g2, be2, m2, v2,
        c3w, c3b, g3, be3, m3, v3,
        a1, a2t, a3);
    gap_row_kernel<<<B * H, 256, 0, stream>>>(x, a3, gpart);
    se_kernel<<<B, 256, 0, stream>>>(gpart, a1, pavg1, a2t, pavg2, sw1, sb1, sw2, sb2, cwv);
    out_row_kernel<<<B * H, 256, 0, stream>>>(x, a1, a2t, a3, cwv, (float*)d_out);
}